// Round 12
// baseline (946.717 us; speedup 1.0000x reference)
//
#include <hip/hip_runtime.h>
#include <hip/hip_bf16.h>

// GroupedMLP: E=8, T=1024, H=2048, I=5632
// Round 11: ring-3 schedule kept EXACTLY (1 barrier + counted vmcnt/tile,
// stage(t+2) after barrier, G2-swizzled ws). Single variable vs r10: wave
// geometry 16x(64x64) -> 8x(128x64). LDS reads per K-32 tile drop 128->96KB
// (below the 1243-cyc MFMA pipe) because per-wave read cost scales with
// (Mw+Nw) while FLOPs scale with Mw*Nw. 512 threads, acc[8][4] (~128 regs).

#define EXPERTS 8
#define TOK     1024
#define HID     2048
#define INTER   5632
#define I2      (2 * INTER)

typedef __bf16 bf16x8 __attribute__((ext_vector_type(8)));
typedef float  f32x4  __attribute__((ext_vector_type(4)));

#define G2(row) ((((row) >> 1) & 3) << 3)   // element-index XOR, bits 3-4

__device__ __forceinline__ unsigned short f2bf(float f) {
    union { float f; unsigned u; } v; v.f = f;
    unsigned r = v.u + 0x7FFFu + ((v.u >> 16) & 1u);   // RNE
    return (unsigned short)(r >> 16);
}

__device__ __forceinline__ void gload_lds16(const void* g, void* l) {
    __builtin_amdgcn_global_load_lds(
        (const __attribute__((address_space(1))) void*)g,
        (__attribute__((address_space(3))) void*)l, 16, 0, 0);
}

// fragment read from a [rows][32] bf16 tile, swizzled by G2(row)
__device__ __forceinline__ bf16x8 ldfrag(const unsigned short* S, int R, int kb) {
    int off = R * 32 + (kb ^ G2(R));
    return *reinterpret_cast<const bf16x8*>(S + off);
}

// ---------------- converts (identical to round 10: G2-swizzled ws) ----------------

__global__ __launch_bounds__(256) void k_cvt_x(const float* __restrict__ X,
                                               unsigned short* __restrict__ Xb) {
    size_t base = ((size_t)blockIdx.x * 256 + threadIdx.x) * 8;
    int row = (int)(base >> 11);
    int k   = (int)(base & (HID - 1));
    int kp  = k ^ G2(row);
    float4 v0 = *reinterpret_cast<const float4*>(X + base);
    float4 v1 = *reinterpret_cast<const float4*>(X + base + 4);
    uint4 o;
    o.x = (unsigned)f2bf(v0.x) | ((unsigned)f2bf(v0.y) << 16);
    o.y = (unsigned)f2bf(v0.z) | ((unsigned)f2bf(v0.w) << 16);
    o.z = (unsigned)f2bf(v1.x) | ((unsigned)f2bf(v1.y) << 16);
    o.w = (unsigned)f2bf(v1.z) | ((unsigned)f2bf(v1.w) << 16);
    *reinterpret_cast<uint4*>(Xb + (size_t)row * HID + kp) = o;
}

__global__ __launch_bounds__(256) void k_cvt_w1(const float* __restrict__ W1,
                                                unsigned short* __restrict__ W1T) {
    __shared__ unsigned short lds[64][72];
    const int bid = blockIdx.x;
    const int hb = bid % (HID / 64);
    const int pb = (bid / (HID / 64)) % (I2 / 64);
    const int e  = bid / ((HID / 64) * (I2 / 64));
    const int h0 = hb * 64, p0 = pb * 64, n0 = p0 >> 1;
    const float* w1e = W1 + (size_t)e * HID * I2;
    const int t = threadIdx.x;
#pragma unroll
    for (int it = 0; it < 16; ++it) {
        int lin   = it * 256 + t;
        int n_off = lin & 31;
        int c     = (lin >> 5) & 1;
        int h_off = lin >> 6;
        float v = w1e[(size_t)(h0 + h_off) * I2 + c * INTER + n0 + n_off];
        lds[2 * n_off + c][h_off] = f2bf(v);
    }
    __syncthreads();
    unsigned short* o = W1T + (size_t)e * I2 * HID;
#pragma unroll
    for (int it = 0; it < 4; ++it) {
        int lin = it * 256 + t;
        int r   = lin >> 4;
        int co  = (lin & 15) * 4;
        int cop = co ^ G2(r);
        ushort4 v = *reinterpret_cast<ushort4*>(&lds[r][co]);
        *reinterpret_cast<ushort4*>(o + (size_t)(p0 + r) * HID + h0 + cop) = v;
    }
}

__global__ __launch_bounds__(256) void k_cvt_w2(const float* __restrict__ W2,
                                                unsigned short* __restrict__ W2T) {
    __shared__ unsigned short lds[64][72];
    const int bid = blockIdx.x;
    const int ib = bid % (INTER / 64);
    const int hb = (bid / (INTER / 64)) % (HID / 64);
    const int e  = bid / ((INTER / 64) * (HID / 64));
    const int i0 = ib * 64, h0 = hb * 64;
    const float* w2e = W2 + (size_t)e * INTER * HID;
    const int t = threadIdx.x;
#pragma unroll
    for (int it = 0; it < 16; ++it) {
        int lin   = it * 256 + t;
        int h_off = lin & 63;
        int i_off = lin >> 6;
        float v = w2e[(size_t)(i0 + i_off) * HID + h0 + h_off];
        lds[h_off][i_off] = f2bf(v);
    }
    __syncthreads();
    unsigned short* o = W2T + (size_t)e * HID * INTER;
#pragma unroll
    for (int it = 0; it < 4; ++it) {
        int lin = it * 256 + t;
        int r   = lin >> 4;
        int co  = (lin & 15) * 4;
        int cop = co ^ G2(r);
        ushort4 v = *reinterpret_cast<ushort4*>(&lds[r][co]);
        *reinterpret_cast<ushort4*>(o + (size_t)(h0 + r) * INTER + i0 + cop) = v;
    }
}

// ---------------- ring-3 GEMM core: 256x256 tile, BK=32, 8 waves of 128x64 ----
// Buffer (32KB = 16384 ushorts): A [256][32] at 0, B [256][32] at +8192.
// Stage: 2 A + 2 B gload_lds16 per thread (512 threads), linear dest.

__device__ __forceinline__ void stage32(const unsigned short* Ab, const unsigned short* Bb,
                                        int ktot, int k0, unsigned short* buf, int t) {
#pragma unroll
    for (int j = 0; j < 2; ++j) {
        int lin = j * 512 + t;
        int row = lin >> 2;
        int col = (lin & 3) * 8;
        gload_lds16(Ab + (size_t)row * ktot + k0 + col, buf + lin * 8);
        gload_lds16(Bb + (size_t)row * ktot + k0 + col, buf + 8192 + lin * 8);
    }
}

#define MFMA_BF16(a, b, c) __builtin_amdgcn_mfma_f32_16x16x32_bf16(a, b, c, 0, 0, 0)

__device__ __forceinline__ void gemm_ring3(const unsigned short* Ab, const unsigned short* Bb,
                                           int ktot, int nkt, f32x4 (&acc)[8][4],
                                           unsigned short* lds, int t, int lane,
                                           int wr, int wc) {
    const int cl  = lane & 15;
    const int kb0 = (lane >> 4) << 3;

    // prologue: stage tiles 0 and 1 (8 loads outstanding)
    stage32(Ab, Bb, ktot, 0,  lds,         t);
    stage32(Ab, Bb, ktot, 32, lds + 16384, t);

    int c_cur = 0, c_n2 = 2;
    for (int kt = 0; kt < nkt; ++kt) {
        if (kt + 1 < nkt) { asm volatile("s_waitcnt vmcnt(4)" ::: "memory"); }
        else              { asm volatile("s_waitcnt vmcnt(0)" ::: "memory"); }
        __builtin_amdgcn_s_barrier();   // buf[c_cur] landed everywhere; buf[c_n2] free
        asm volatile("" ::: "memory");

        unsigned short* Ac = lds + c_cur * 16384;
        unsigned short* Bc = Ac + 8192;

        if (kt + 2 < nkt)
            stage32(Ab, Bb, ktot, (kt + 2) * 32, lds + c_n2 * 16384, t);

        bf16x8 b[4], a[2];
#pragma unroll
        for (int n = 0; n < 4; ++n)
            b[n] = ldfrag(Bc, wc + n * 16 + cl, kb0);
        a[0] = ldfrag(Ac, wr + cl, kb0);

#pragma unroll
        for (int m = 0; m < 8; ++m) {
            if (m < 7)
                a[(m + 1) & 1] = ldfrag(Ac, wr + (m + 1) * 16 + cl, kb0);
            __builtin_amdgcn_s_setprio(1);
#pragma unroll
            for (int n = 0; n < 4; ++n)
                acc[m][n] = MFMA_BF16(a[m & 1], b[n], acc[m][n]);
            __builtin_amdgcn_s_setprio(0);
        }

        c_cur = (c_cur == 2) ? 0 : c_cur + 1;
        c_n2  = (c_n2  == 2) ? 0 : c_n2  + 1;
    }
}

// fc1: Xb @ w1t^T -> inter bf16 (GLU fused, G2-swizzled store)
__global__ __launch_bounds__(512, 2) void k_fc1_r3(const unsigned short* __restrict__ Xb,
                                                   const unsigned short* __restrict__ W1T,
                                                   unsigned short* __restrict__ inter) {
    extern __shared__ unsigned short lds[];
    const int bid = blockIdx.x;                // 1408 = 8 XCD * (4 mt * 44 nt)
    const int e   = bid & 7;
    const int idx = bid >> 3;
    const int mt  = idx & 3;                   // mt innermost: B-panel shared
    const int nt  = idx >> 2;                  // 0..43
    const int t = threadIdx.x, lane = t & 63, w = t >> 6;
    const int wr = (w >> 2) * 128;             // 2 M-groups of 128
    const int wc = (w & 3) * 64;               // 4 N-groups of 64
    const int m0 = e * TOK + mt * 256;
    const int n0 = nt * 256;                   // pc-space
    const unsigned short* Ab = Xb  + (size_t)m0 * HID;
    const unsigned short* Bb = W1T + (size_t)e * I2 * HID + (size_t)n0 * HID;

    f32x4 acc[8][4];
#pragma unroll
    for (int i = 0; i < 8; ++i)
#pragma unroll
        for (int j = 0; j < 4; ++j) acc[i][j] = f32x4{0.f, 0.f, 0.f, 0.f};

    gemm_ring3(Ab, Bb, HID, HID / 32, acc, lds, t, lane, wr, wc);

    const int cl = lane & 15;
    const int r0 = (lane >> 4) << 2;
#pragma unroll
    for (int mf = 0; mf < 8; ++mf)
#pragma unroll
        for (int nf = 0; nf < 4; ++nf)
#pragma unroll
            for (int r = 0; r < 4; ++r) {
                float v  = acc[mf][nf][r];
                float pv = __shfl_xor(v, 1);
                if ((lane & 1) == 0) {
                    float s = v / (1.f + __expf(-v)) * pv;
                    int row = m0 + wr + mf * 16 + r0 + r;
                    int pc  = n0 + wc + nf * 16 + cl;
                    int c   = pc >> 1;
                    int c2  = (c & ~31) | ((c & 31) ^ G2(row));  // fc2-A swizzle
                    inter[(size_t)row * INTER + c2] = f2bf(s);
                }
            }
}

// fc2: inter @ w2t^T -> out fp32
__global__ __launch_bounds__(512, 2) void k_fc2_r3(const unsigned short* __restrict__ A,
                                                   const unsigned short* __restrict__ W2T,
                                                   float* __restrict__ out) {
    extern __shared__ unsigned short lds[];
    const int bid = blockIdx.x;                // 256 = 8 XCD * (4 mt * 8 nt)
    const int e   = bid & 7;
    const int idx = bid >> 3;
    const int mt  = idx & 3;
    const int nt  = idx >> 2;                  // 0..7
    const int t = threadIdx.x, lane = t & 63, w = t >> 6;
    const int wr = (w >> 2) * 128;
    const int wc = (w & 3) * 64;
    const int m0 = e * TOK + mt * 256;
    const int n0 = nt * 256;
    const unsigned short* Ab = A   + (size_t)m0 * INTER;
    const unsigned short* Bb = W2T + (size_t)e * HID * INTER + (size_t)n0 * INTER;

    f32x4 acc[8][4];
#pragma unroll
    for (int i = 0; i < 8; ++i)
#pragma unroll
        for (int j = 0; j < 4; ++j) acc[i][j] = f32x4{0.f, 0.f, 0.f, 0.f};

    gemm_ring3(Ab, Bb, INTER, INTER / 32, acc, lds, t, lane, wr, wc);

    const int cl = lane & 15;
    const int r0 = (lane >> 4) << 2;
#pragma unroll
    for (int mf = 0; mf < 8; ++mf)
#pragma unroll
        for (int nf = 0; nf < 4; ++nf)
#pragma unroll
            for (int r = 0; r < 4; ++r) {
                int row = m0 + wr + mf * 16 + r0 + r;
                int col = n0 + wc + nf * 16 + cl;
                out[(size_t)row * HID + col] = acc[mf][nf][r];
            }
}

// ---------------- fallback (round-1 kernels, need only 92 MB ws) ----------------

#define BM  128
#define BK  64
#define LDK 72

__global__ __launch_bounds__(256) void k_fc1_glu_fb(
    const float* __restrict__ X, const float* __restrict__ W1,
    unsigned short* __restrict__ inter)
{
    __shared__ unsigned short As[BM][LDK];
    __shared__ unsigned short Bs[128][LDK];
    const int bid = blockIdx.x;
    const int nt  = bid % (INTER / 64);
    const int mt  = (bid / (INTER / 64)) % (TOK / BM);
    const int e   = bid / ((INTER / 64) * (TOK / BM));
    const int t = threadIdx.x, lane = t & 63, w = t >> 6;
    const int m0 = mt * BM;
    const int rowbase = e * TOK + m0;
    f32x4 acc[2][8];
#pragma unroll
    for (int i = 0; i < 2; ++i)
#pragma unroll
        for (int jj = 0; jj < 8; ++jj) acc[i][jj] = f32x4{0.f, 0.f, 0.f, 0.f};
    const int jcol = t & 127;
    const int hf   = t >> 7;
    const int gcol = (jcol < 64) ? (nt * 64 + jcol) : (INTER + nt * 64 + (jcol - 64));
    const float* w1e = W1 + (size_t)e * HID * I2;
    for (int k0 = 0; k0 < HID; k0 += BK) {
#pragma unroll
        for (int it = 0; it < 8; ++it) {
            int lin = it * 256 + t;
            int r   = lin >> 4;
            int kq  = (lin & 15) << 2;
            const float4 v = *reinterpret_cast<const float4*>(
                X + (size_t)(rowbase + r) * HID + k0 + kq);
            ushort4 o;
            o.x = f2bf(v.x); o.y = f2bf(v.y); o.z = f2bf(v.z); o.w = f2bf(v.w);
            *reinterpret_cast<ushort4*>(&As[r][kq]) = o;
        }
#pragma unroll
        for (int it = 0; it < 8; ++it) {
            int kq = hf * 4 + it * 8;
            const float* p = w1e + (size_t)(k0 + kq) * I2 + gcol;
            float v0 = p[0], v1 = p[I2], v2 = p[2 * I2], v3 = p[3 * I2];
            ushort4 o;
            o.x = f2bf(v0); o.y = f2bf(v1); o.z = f2bf(v2); o.w = f2bf(v3);
            *reinterpret_cast<ushort4*>(&Bs[jcol][kq]) = o;
        }
        __syncthreads();
#pragma unroll
        for (int kk = 0; kk < 2; ++kk) {
            const int kb = kk * 32 + ((lane >> 4) << 3);
            bf16x8 a0 = *reinterpret_cast<const bf16x8*>(&As[w * 32 + (lane & 15)][kb]);
            bf16x8 a1 = *reinterpret_cast<const bf16x8*>(&As[w * 32 + 16 + (lane & 15)][kb]);
#pragma unroll
            for (int nf = 0; nf < 8; ++nf) {
                bf16x8 b = *reinterpret_cast<const bf16x8*>(&Bs[nf * 16 + (lane & 15)][kb]);
                acc[0][nf] = MFMA_BF16(a0, b, acc[0][nf]);
                acc[1][nf] = MFMA_BF16(a1, b, acc[1][nf]);
            }
        }
        __syncthreads();
    }
    const int rl0 = w * 32 + ((lane >> 4) << 2);
    const int cl  = lane & 15;
#pragma unroll
    for (int mf = 0; mf < 2; ++mf)
#pragma unroll
        for (int nfa = 0; nfa < 4; ++nfa) {
            f32x4 va = acc[mf][nfa];
            f32x4 vb = acc[mf][nfa + 4];
#pragma unroll
            for (int r = 0; r < 4; ++r) {
                float a = va[r], b = vb[r];
                float s = a / (1.f + __expf(-a)) * b;
                int row = rowbase + rl0 + mf * 16 + r;
                int col = nt * 64 + nfa * 16 + cl;
                inter[(size_t)row * INTER + col] = f2bf(s);
            }
        }
}

__global__ __launch_bounds__(256) void k_fc2_fb(
    const unsigned short* __restrict__ inter, const float* __restrict__ W2,
    float* __restrict__ out)
{
    __shared__ unsigned short As[BM][LDK];
    __shared__ unsigned short Bs[128][LDK];
    const int bid = blockIdx.x;
    const int nt  = bid % (HID / 128);
    const int mt  = (bid / (HID / 128)) % (TOK / BM);
    const int e   = bid / ((HID / 128) * (TOK / BM));
    const int t = threadIdx.x, lane = t & 63, w = t >> 6;
    const int m0 = mt * BM;
    const int rowbase = e * TOK + m0;
    f32x4 acc[2][8];
#pragma unroll
    for (int i = 0; i < 2; ++i)
#pragma unroll
        for (int jj = 0; jj < 8; ++jj) acc[i][jj] = f32x4{0.f, 0.f, 0.f, 0.f};
    const int jcol = t & 127;
    const int hf   = t >> 7;
    const int gcol = nt * 128 + jcol;
    const float* w2e = W2 + (size_t)e * INTER * HID;
    for (int k0 = 0; k0 < INTER; k0 += BK) {
#pragma unroll
        for (int it = 0; it < 4; ++it) {
            int lin = it * 256 + t;
            int r   = lin >> 3;
            int kq  = (lin & 7) << 3;
            uint4 v = *reinterpret_cast<const uint4*>(
                inter + (size_t)(rowbase + r) * INTER + k0 + kq);
            *reinterpret_cast<uint4*>(&As[r][kq]) = v;
        }
#pragma unroll
        for (int it = 0; it < 8; ++it) {
            int kq = hf * 4 + it * 8;
            const float* p = w2e + (size_t)(k0 + kq) * HID + gcol;
            float v0 = p[0], v1 = p[HID], v2 = p[2 * HID], v3 = p[3 * HID];
            ushort4 o;
            o.x = f2bf(v0); o.y = f2bf(v1); o.z = f2bf(v2); o.w = f2bf(v3);
            *reinterpret_cast<ushort4*>(&Bs[jcol][kq]) = o;
        }
        __syncthreads();
#pragma unroll
        for (int kk = 0; kk < 2; ++kk) {
            const int kb = kk * 32 + ((lane >> 4) << 3);
            bf16x8 a0 = *reinterpret_cast<const bf16x8*>(&As[w * 32 + (lane & 15)][kb]);
            bf16x8 a1 = *reinterpret_cast<const bf16x8*>(&As[w * 32 + 16 + (lane & 15)][kb]);
#pragma unroll
            for (int nf = 0; nf < 8; ++nf) {
                bf16x8 b = *reinterpret_cast<const bf16x8*>(&Bs[nf * 16 + (lane & 15)][kb]);
                acc[0][nf] = MFMA_BF16(a0, b, acc[0][nf]);
                acc[1][nf] = MFMA_BF16(a1, b, acc[1][nf]);
            }
        }
        __syncthreads();
    }
    const int rl0 = w * 32 + ((lane >> 4) << 2);
    const int cl  = lane & 15;
#pragma unroll
    for (int mf = 0; mf < 2; ++mf)
#pragma unroll
        for (int nf = 0; nf < 8; ++nf) {
            f32x4 v = acc[mf][nf];
#pragma unroll
            for (int r = 0; r < 4; ++r) {
                int row = rowbase + rl0 + mf * 16 + r;
                int col = nt * 128 + nf * 16 + cl;
                out[(size_t)row * HID + col] = v[r];
            }
        }
}

// ---------------- launch ----------------

extern "C" void kernel_launch(void* const* d_in, const int* in_sizes, int n_in,
                              void* d_out, int out_size, void* d_ws, size_t ws_size,
                              hipStream_t stream) {
    const float* X  = (const float*)d_in[0];
    const float* W1 = (const float*)d_in[1];
    const float* W2 = (const float*)d_in[2];
    float* out = (float*)d_out;

    const size_t XB_B  = (size_t)EXPERTS * TOK * HID * 2;
    const size_t W1T_B = (size_t)EXPERTS * I2 * HID * 2;
    const size_t W2T_B = (size_t)EXPERTS * HID * INTER * 2;
    const size_t INT_B = (size_t)EXPERTS * TOK * INTER * 2;
    const size_t need  = XB_B + W1T_B + W2T_B + INT_B;

    if (ws_size >= need) {
        unsigned short* Xb    = (unsigned short*)d_ws;
        unsigned short* w1t   = (unsigned short*)((char*)d_ws + XB_B);
        unsigned short* w2t   = (unsigned short*)((char*)d_ws + XB_B + W1T_B);
        unsigned short* inter = (unsigned short*)((char*)d_ws + XB_B + W1T_B + W2T_B);

        hipFuncSetAttribute((const void*)k_fc1_r3,
            hipFuncAttributeMaxDynamicSharedMemorySize, 98304);
        hipFuncSetAttribute((const void*)k_fc2_r3,
            hipFuncAttributeMaxDynamicSharedMemorySize, 98304);

        dim3 b256(256), b512(512);
        k_cvt_x <<<(EXPERTS * TOK * HID) / (256 * 8), b256, 0, stream>>>(X, Xb);
        k_cvt_w1<<<EXPERTS * (I2 / 64) * (HID / 64),   b256, 0, stream>>>(W1, w1t);
        k_cvt_w2<<<EXPERTS * (HID / 64) * (INTER / 64), b256, 0, stream>>>(W2, w2t);
        k_fc1_r3<<<EXPERTS * 4 * (I2 / 256),  b512, 98304, stream>>>(Xb, w1t, inter);
        k_fc2_r3<<<EXPERTS * 4 * (HID / 256), b512, 98304, stream>>>(inter, w2t, out);
    } else {
        unsigned short* inter = (unsigned short*)d_ws;
        dim3 b256(256);
        k_fc1_glu_fb<<<EXPERTS * (TOK / BM) * (INTER / 64), b256, 0, stream>>>(X, W1, inter);
        k_fc2_fb    <<<EXPERTS * (TOK / BM) * (HID / 128),  b256, 0, stream>>>(inter, W2, out);
    }
}

// Round 13
// 938.638 us; speedup vs baseline: 1.0086x; 1.0086x over previous
//
#include <hip/hip_runtime.h>
#include <hip/hip_bf16.h>

// GroupedMLP: E=8, T=1024, H=2048, I=5632
// Round 12: single variable vs r10 — TWO independent 8-wave blocks per CU
// instead of one 16-wave block. 256x128 tile, BK=32, ring-3 x 24KB = 72KB
// LDS (2 blocks/CU = 144KB), 512 threads, acc[4][4] (~108 VGPR, bounds(512,4)).
// Mechanism: r9-r11 showed per-K-tile time pinned at ~3000cyc regardless of
// BK/geometry -> lockstep-domain latency, not pipe throughput. Two barrier
// domains let one block's waves issue while the other stalls (m114). r7's
// negative occupancy result was confounded by its broken swizzle (4.6e7
// conflicts); G2 swizzle here is verified 0-conflict (r10/r11).

#define EXPERTS 8
#define TOK     1024
#define HID     2048
#define INTER   5632
#define I2      (2 * INTER)

typedef __bf16 bf16x8 __attribute__((ext_vector_type(8)));
typedef float  f32x4  __attribute__((ext_vector_type(4)));

#define G2(row) ((((row) >> 1) & 3) << 3)   // element-index XOR, bits 3-4

__device__ __forceinline__ unsigned short f2bf(float f) {
    union { float f; unsigned u; } v; v.f = f;
    unsigned r = v.u + 0x7FFFu + ((v.u >> 16) & 1u);   // RNE
    return (unsigned short)(r >> 16);
}

__device__ __forceinline__ void gload_lds16(const void* g, void* l) {
    __builtin_amdgcn_global_load_lds(
        (const __attribute__((address_space(1))) void*)g,
        (__attribute__((address_space(3))) void*)l, 16, 0, 0);
}

// fragment read from a [rows][32] bf16 tile, swizzled by G2(row)
__device__ __forceinline__ bf16x8 ldfrag(const unsigned short* S, int R, int kb) {
    int off = R * 32 + (kb ^ G2(R));
    return *reinterpret_cast<const bf16x8*>(S + off);
}

// ---------------- converts (identical to r10/r11: G2-swizzled ws) ----------------

__global__ __launch_bounds__(256) void k_cvt_x(const float* __restrict__ X,
                                               unsigned short* __restrict__ Xb) {
    size_t base = ((size_t)blockIdx.x * 256 + threadIdx.x) * 8;
    int row = (int)(base >> 11);
    int k   = (int)(base & (HID - 1));
    int kp  = k ^ G2(row);
    float4 v0 = *reinterpret_cast<const float4*>(X + base);
    float4 v1 = *reinterpret_cast<const float4*>(X + base + 4);
    uint4 o;
    o.x = (unsigned)f2bf(v0.x) | ((unsigned)f2bf(v0.y) << 16);
    o.y = (unsigned)f2bf(v0.z) | ((unsigned)f2bf(v0.w) << 16);
    o.z = (unsigned)f2bf(v1.x) | ((unsigned)f2bf(v1.y) << 16);
    o.w = (unsigned)f2bf(v1.z) | ((unsigned)f2bf(v1.w) << 16);
    *reinterpret_cast<uint4*>(Xb + (size_t)row * HID + kp) = o;
}

__global__ __launch_bounds__(256) void k_cvt_w1(const float* __restrict__ W1,
                                                unsigned short* __restrict__ W1T) {
    __shared__ unsigned short lds[64][72];
    const int bid = blockIdx.x;
    const int hb = bid % (HID / 64);
    const int pb = (bid / (HID / 64)) % (I2 / 64);
    const int e  = bid / ((HID / 64) * (I2 / 64));
    const int h0 = hb * 64, p0 = pb * 64, n0 = p0 >> 1;
    const float* w1e = W1 + (size_t)e * HID * I2;
    const int t = threadIdx.x;
#pragma unroll
    for (int it = 0; it < 16; ++it) {
        int lin   = it * 256 + t;
        int n_off = lin & 31;
        int c     = (lin >> 5) & 1;
        int h_off = lin >> 6;
        float v = w1e[(size_t)(h0 + h_off) * I2 + c * INTER + n0 + n_off];
        lds[2 * n_off + c][h_off] = f2bf(v);
    }
    __syncthreads();
    unsigned short* o = W1T + (size_t)e * I2 * HID;
#pragma unroll
    for (int it = 0; it < 4; ++it) {
        int lin = it * 256 + t;
        int r   = lin >> 4;
        int co  = (lin & 15) * 4;
        int cop = co ^ G2(r);
        ushort4 v = *reinterpret_cast<ushort4*>(&lds[r][co]);
        *reinterpret_cast<ushort4*>(o + (size_t)(p0 + r) * HID + h0 + cop) = v;
    }
}

__global__ __launch_bounds__(256) void k_cvt_w2(const float* __restrict__ W2,
                                                unsigned short* __restrict__ W2T) {
    __shared__ unsigned short lds[64][72];
    const int bid = blockIdx.x;
    const int ib = bid % (INTER / 64);
    const int hb = (bid / (INTER / 64)) % (HID / 64);
    const int e  = bid / ((INTER / 64) * (HID / 64));
    const int i0 = ib * 64, h0 = hb * 64;
    const float* w2e = W2 + (size_t)e * INTER * HID;
    const int t = threadIdx.x;
#pragma unroll
    for (int it = 0; it < 16; ++it) {
        int lin   = it * 256 + t;
        int h_off = lin & 63;
        int i_off = lin >> 6;
        float v = w2e[(size_t)(i0 + i_off) * HID + h0 + h_off];
        lds[h_off][i_off] = f2bf(v);
    }
    __syncthreads();
    unsigned short* o = W2T + (size_t)e * HID * INTER;
#pragma unroll
    for (int it = 0; it < 4; ++it) {
        int lin = it * 256 + t;
        int r   = lin >> 4;
        int co  = (lin & 15) * 4;
        int cop = co ^ G2(r);
        ushort4 v = *reinterpret_cast<ushort4*>(&lds[r][co]);
        *reinterpret_cast<ushort4*>(o + (size_t)(h0 + r) * INTER + i0 + cop) = v;
    }
}

// ---------------- ring-3 GEMM core: 256x128 tile, BK=32, 8 waves of 64x64 ----
// Buffer (24KB = 12288 ushorts): A [256][32] at 0, B [128][32] at +8192.
// Stage: 2 A + 1 B gload_lds16 per thread (512 threads), linear dest.

__device__ __forceinline__ void stage24(const unsigned short* Ab, const unsigned short* Bb,
                                        int ktot, int k0, unsigned short* buf, int t) {
#pragma unroll
    for (int j = 0; j < 2; ++j) {
        int lin = j * 512 + t;
        int row = lin >> 2;
        int col = (lin & 3) * 8;
        gload_lds16(Ab + (size_t)row * ktot + k0 + col, buf + lin * 8);
    }
    {
        int row = t >> 2;
        int col = (t & 3) * 8;
        gload_lds16(Bb + (size_t)row * ktot + k0 + col, buf + 8192 + t * 8);
    }
}

#define MFMA_BF16(a, b, c) __builtin_amdgcn_mfma_f32_16x16x32_bf16(a, b, c, 0, 0, 0)

__device__ __forceinline__ void gemm_ring3(const unsigned short* Ab, const unsigned short* Bb,
                                           int ktot, int nkt, f32x4 (&acc)[4][4],
                                           unsigned short* lds, int t, int lane,
                                           int wr, int wc) {
    const int cl  = lane & 15;
    const int kb0 = (lane >> 4) << 3;

    // prologue: stage tiles 0 and 1 (6 loads outstanding)
    stage24(Ab, Bb, ktot, 0,  lds,         t);
    stage24(Ab, Bb, ktot, 32, lds + 12288, t);

    int c_cur = 0, c_n2 = 2;
    for (int kt = 0; kt < nkt; ++kt) {
        if (kt + 1 < nkt) { asm volatile("s_waitcnt vmcnt(3)" ::: "memory"); }
        else              { asm volatile("s_waitcnt vmcnt(0)" ::: "memory"); }
        __builtin_amdgcn_s_barrier();   // buf[c_cur] landed everywhere; buf[c_n2] free
        asm volatile("" ::: "memory");

        unsigned short* Ac = lds + c_cur * 12288;
        unsigned short* Bc = Ac + 8192;

        if (kt + 2 < nkt)
            stage24(Ab, Bb, ktot, (kt + 2) * 32, lds + c_n2 * 12288, t);

        bf16x8 b[4], a[2];
#pragma unroll
        for (int n = 0; n < 4; ++n)
            b[n] = ldfrag(Bc, wc + n * 16 + cl, kb0);
        a[0] = ldfrag(Ac, wr + cl, kb0);

#pragma unroll
        for (int m = 0; m < 4; ++m) {
            if (m < 3)
                a[(m + 1) & 1] = ldfrag(Ac, wr + (m + 1) * 16 + cl, kb0);
            __builtin_amdgcn_s_setprio(1);
#pragma unroll
            for (int n = 0; n < 4; ++n)
                acc[m][n] = MFMA_BF16(a[m & 1], b[n], acc[m][n]);
            __builtin_amdgcn_s_setprio(0);
        }

        c_cur = (c_cur == 2) ? 0 : c_cur + 1;
        c_n2  = (c_n2  == 2) ? 0 : c_n2  + 1;
    }
}

// fc1: Xb @ w1t^T -> inter bf16 (GLU fused, G2-swizzled store)
__global__ __launch_bounds__(512, 4) void k_fc1_r3(const unsigned short* __restrict__ Xb,
                                                   const unsigned short* __restrict__ W1T,
                                                   unsigned short* __restrict__ inter) {
    extern __shared__ unsigned short lds[];
    const int bid = blockIdx.x;                // 2816 = 8 XCD * (4 mt * 88 nt)
    const int e   = bid & 7;
    const int idx = bid >> 3;
    const int mt  = idx & 3;                   // mt innermost: B-panel shared
    const int nt  = idx >> 2;                  // 0..87
    const int t = threadIdx.x, lane = t & 63, w = t >> 6;
    const int wr = (w >> 1) * 64;              // 4 M-groups of 64
    const int wc = (w & 1) * 64;               // 2 N-groups of 64
    const int m0 = e * TOK + mt * 256;
    const int n0 = nt * 128;                   // pc-space
    const unsigned short* Ab = Xb  + (size_t)m0 * HID;
    const unsigned short* Bb = W1T + (size_t)e * I2 * HID + (size_t)n0 * HID;

    f32x4 acc[4][4];
#pragma unroll
    for (int i = 0; i < 4; ++i)
#pragma unroll
        for (int j = 0; j < 4; ++j) acc[i][j] = f32x4{0.f, 0.f, 0.f, 0.f};

    gemm_ring3(Ab, Bb, HID, HID / 32, acc, lds, t, lane, wr, wc);

    const int cl = lane & 15;
    const int r0 = (lane >> 4) << 2;
#pragma unroll
    for (int mf = 0; mf < 4; ++mf)
#pragma unroll
        for (int nf = 0; nf < 4; ++nf)
#pragma unroll
            for (int r = 0; r < 4; ++r) {
                float v  = acc[mf][nf][r];
                float pv = __shfl_xor(v, 1);
                if ((lane & 1) == 0) {
                    float s = v / (1.f + __expf(-v)) * pv;
                    int row = m0 + wr + mf * 16 + r0 + r;
                    int pc  = n0 + wc + nf * 16 + cl;
                    int c   = pc >> 1;
                    int c2  = (c & ~31) | ((c & 31) ^ G2(row));  // fc2-A swizzle
                    inter[(size_t)row * INTER + c2] = f2bf(s);
                }
            }
}

// fc2: inter @ w2t^T -> out fp32
__global__ __launch_bounds__(512, 4) void k_fc2_r3(const unsigned short* __restrict__ A,
                                                   const unsigned short* __restrict__ W2T,
                                                   float* __restrict__ out) {
    extern __shared__ unsigned short lds[];
    const int bid = blockIdx.x;                // 512 = 8 XCD * (4 mt * 16 nt)
    const int e   = bid & 7;
    const int idx = bid >> 3;
    const int mt  = idx & 3;
    const int nt  = idx >> 2;                  // 0..15
    const int t = threadIdx.x, lane = t & 63, w = t >> 6;
    const int wr = (w >> 1) * 64;
    const int wc = (w & 1) * 64;
    const int m0 = e * TOK + mt * 256;
    const int n0 = nt * 128;
    const unsigned short* Ab = A   + (size_t)m0 * INTER;
    const unsigned short* Bb = W2T + (size_t)e * HID * INTER + (size_t)n0 * INTER;

    f32x4 acc[4][4];
#pragma unroll
    for (int i = 0; i < 4; ++i)
#pragma unroll
        for (int j = 0; j < 4; ++j) acc[i][j] = f32x4{0.f, 0.f, 0.f, 0.f};

    gemm_ring3(Ab, Bb, INTER, INTER / 32, acc, lds, t, lane, wr, wc);

    const int cl = lane & 15;
    const int r0 = (lane >> 4) << 2;
#pragma unroll
    for (int mf = 0; mf < 4; ++mf)
#pragma unroll
        for (int nf = 0; nf < 4; ++nf)
#pragma unroll
            for (int r = 0; r < 4; ++r) {
                int row = m0 + wr + mf * 16 + r0 + r;
                int col = n0 + wc + nf * 16 + cl;
                out[(size_t)row * HID + col] = acc[mf][nf][r];
            }
}

// ---------------- fallback (round-1 kernels, need only 92 MB ws) ----------------

#define BM  128
#define BK  64
#define LDK 72

__global__ __launch_bounds__(256) void k_fc1_glu_fb(
    const float* __restrict__ X, const float* __restrict__ W1,
    unsigned short* __restrict__ inter)
{
    __shared__ unsigned short As[BM][LDK];
    __shared__ unsigned short Bs[128][LDK];
    const int bid = blockIdx.x;
    const int nt  = bid % (INTER / 64);
    const int mt  = (bid / (INTER / 64)) % (TOK / BM);
    const int e   = bid / ((INTER / 64) * (TOK / BM));
    const int t = threadIdx.x, lane = t & 63, w = t >> 6;
    const int m0 = mt * BM;
    const int rowbase = e * TOK + m0;
    f32x4 acc[2][8];
#pragma unroll
    for (int i = 0; i < 2; ++i)
#pragma unroll
        for (int jj = 0; jj < 8; ++jj) acc[i][jj] = f32x4{0.f, 0.f, 0.f, 0.f};
    const int jcol = t & 127;
    const int hf   = t >> 7;
    const int gcol = (jcol < 64) ? (nt * 64 + jcol) : (INTER + nt * 64 + (jcol - 64));
    const float* w1e = W1 + (size_t)e * HID * I2;
    for (int k0 = 0; k0 < HID; k0 += BK) {
#pragma unroll
        for (int it = 0; it < 8; ++it) {
            int lin = it * 256 + t;
            int r   = lin >> 4;
            int kq  = (lin & 15) << 2;
            const float4 v = *reinterpret_cast<const float4*>(
                X + (size_t)(rowbase + r) * HID + k0 + kq);
            ushort4 o;
            o.x = f2bf(v.x); o.y = f2bf(v.y); o.z = f2bf(v.z); o.w = f2bf(v.w);
            *reinterpret_cast<ushort4*>(&As[r][kq]) = o;
        }
#pragma unroll
        for (int it = 0; it < 8; ++it) {
            int kq = hf * 4 + it * 8;
            const float* p = w1e + (size_t)(k0 + kq) * I2 + gcol;
            float v0 = p[0], v1 = p[I2], v2 = p[2 * I2], v3 = p[3 * I2];
            ushort4 o;
            o.x = f2bf(v0); o.y = f2bf(v1); o.z = f2bf(v2); o.w = f2bf(v3);
            *reinterpret_cast<ushort4*>(&Bs[jcol][kq]) = o;
        }
        __syncthreads();
#pragma unroll
        for (int kk = 0; kk < 2; ++kk) {
            const int kb = kk * 32 + ((lane >> 4) << 3);
            bf16x8 a0 = *reinterpret_cast<const bf16x8*>(&As[w * 32 + (lane & 15)][kb]);
            bf16x8 a1 = *reinterpret_cast<const bf16x8*>(&As[w * 32 + 16 + (lane & 15)][kb]);
#pragma unroll
            for (int nf = 0; nf < 8; ++nf) {
                bf16x8 b = *reinterpret_cast<const bf16x8*>(&Bs[nf * 16 + (lane & 15)][kb]);
                acc[0][nf] = MFMA_BF16(a0, b, acc[0][nf]);
                acc[1][nf] = MFMA_BF16(a1, b, acc[1][nf]);
            }
        }
        __syncthreads();
    }
    const int rl0 = w * 32 + ((lane >> 4) << 2);
    const int cl  = lane & 15;
#pragma unroll
    for (int mf = 0; mf < 2; ++mf)
#pragma unroll
        for (int nfa = 0; nfa < 4; ++nfa) {
            f32x4 va = acc[mf][nfa];
            f32x4 vb = acc[mf][nfa + 4];
#pragma unroll
            for (int r = 0; r < 4; ++r) {
                float a = va[r], b = vb[r];
                float s = a / (1.f + __expf(-a)) * b;
                int row = rowbase + rl0 + mf * 16 + r;
                int col = nt * 64 + nfa * 16 + cl;
                inter[(size_t)row * INTER + col] = f2bf(s);
            }
        }
}

__global__ __launch_bounds__(256) void k_fc2_fb(
    const unsigned short* __restrict__ inter, const float* __restrict__ W2,
    float* __restrict__ out)
{
    __shared__ unsigned short As[BM][LDK];
    __shared__ unsigned short Bs[128][LDK];
    const int bid = blockIdx.x;
    const int nt  = bid % (HID / 128);
    const int mt  = (bid / (HID / 128)) % (TOK / BM);
    const int e   = bid / ((HID / 128) * (TOK / BM));
    const int t = threadIdx.x, lane = t & 63, w = t >> 6;
    const int m0 = mt * BM;
    const int rowbase = e * TOK + m0;
    f32x4 acc[2][8];
#pragma unroll
    for (int i = 0; i < 2; ++i)
#pragma unroll
        for (int jj = 0; jj < 8; ++jj) acc[i][jj] = f32x4{0.f, 0.f, 0.f, 0.f};
    const int jcol = t & 127;
    const int hf   = t >> 7;
    const int gcol = nt * 128 + jcol;
    const float* w2e = W2 + (size_t)e * INTER * HID;
    for (int k0 = 0; k0 < INTER; k0 += BK) {
#pragma unroll
        for (int it = 0; it < 4; ++it) {
            int lin = it * 256 + t;
            int r   = lin >> 3;
            int kq  = (lin & 7) << 3;
            uint4 v = *reinterpret_cast<const uint4*>(
                inter + (size_t)(rowbase + r) * INTER + k0 + kq);
            *reinterpret_cast<uint4*>(&As[r][kq]) = v;
        }
#pragma unroll
        for (int it = 0; it < 8; ++it) {
            int kq = hf * 4 + it * 8;
            const float* p = w2e + (size_t)(k0 + kq) * HID + gcol;
            float v0 = p[0], v1 = p[HID], v2 = p[2 * HID], v3 = p[3 * HID];
            ushort4 o;
            o.x = f2bf(v0); o.y = f2bf(v1); o.z = f2bf(v2); o.w = f2bf(v3);
            *reinterpret_cast<ushort4*>(&Bs[jcol][kq]) = o;
        }
        __syncthreads();
#pragma unroll
        for (int kk = 0; kk < 2; ++kk) {
            const int kb = kk * 32 + ((lane >> 4) << 3);
            bf16x8 a0 = *reinterpret_cast<const bf16x8*>(&As[w * 32 + (lane & 15)][kb]);
            bf16x8 a1 = *reinterpret_cast<const bf16x8*>(&As[w * 32 + 16 + (lane & 15)][kb]);
#pragma unroll
            for (int nf = 0; nf < 8; ++nf) {
                bf16x8 b = *reinterpret_cast<const bf16x8*>(&Bs[nf * 16 + (lane & 15)][kb]);
                acc[0][nf] = MFMA_BF16(a0, b, acc[0][nf]);
                acc[1][nf] = MFMA_BF16(a1, b, acc[1][nf]);
            }
        }
        __syncthreads();
    }
    const int rl0 = w * 32 + ((lane >> 4) << 2);
    const int cl  = lane & 15;
#pragma unroll
    for (int mf = 0; mf < 2; ++mf)
#pragma unroll
        for (int nf = 0; nf < 8; ++nf) {
            f32x4 v = acc[mf][nf];
#pragma unroll
            for (int r = 0; r < 4; ++r) {
                int row = rowbase + rl0 + mf * 16 + r;
                int col = nt * 128 + nf * 16 + cl;
                out[(size_t)row * HID + col] = v[r];
            }
        }
}

// ---------------- launch ----------------

extern "C" void kernel_launch(void* const* d_in, const int* in_sizes, int n_in,
                              void* d_out, int out_size, void* d_ws, size_t ws_size,
                              hipStream_t stream) {
    const float* X  = (const float*)d_in[0];
    const float* W1 = (const float*)d_in[1];
    const float* W2 = (const float*)d_in[2];
    float* out = (float*)d_out;

    const size_t XB_B  = (size_t)EXPERTS * TOK * HID * 2;
    const size_t W1T_B = (size_t)EXPERTS * I2 * HID * 2;
    const size_t W2T_B = (size_t)EXPERTS * HID * INTER * 2;
    const size_t INT_B = (size_t)EXPERTS * TOK * INTER * 2;
    const size_t need  = XB_B + W1T_B + W2T_B + INT_B;

    if (ws_size >= need) {
        unsigned short* Xb    = (unsigned short*)d_ws;
        unsigned short* w1t   = (unsigned short*)((char*)d_ws + XB_B);
        unsigned short* w2t   = (unsigned short*)((char*)d_ws + XB_B + W1T_B);
        unsigned short* inter = (unsigned short*)((char*)d_ws + XB_B + W1T_B + W2T_B);

        hipFuncSetAttribute((const void*)k_fc1_r3,
            hipFuncAttributeMaxDynamicSharedMemorySize, 73728);
        hipFuncSetAttribute((const void*)k_fc2_r3,
            hipFuncAttributeMaxDynamicSharedMemorySize, 73728);

        dim3 b256(256), b512(512);
        k_cvt_x <<<(EXPERTS * TOK * HID) / (256 * 8), b256, 0, stream>>>(X, Xb);
        k_cvt_w1<<<EXPERTS * (I2 / 64) * (HID / 64),   b256, 0, stream>>>(W1, w1t);
        k_cvt_w2<<<EXPERTS * (HID / 64) * (INTER / 64), b256, 0, stream>>>(W2, w2t);
        k_fc1_r3<<<EXPERTS * 4 * (I2 / 128),  b512, 73728, stream>>>(Xb, w1t, inter);
        k_fc2_r3<<<EXPERTS * 4 * (HID / 128), b512, 73728, stream>>>(inter, w2t, out);
    } else {
        unsigned short* inter = (unsigned short*)d_ws;
        dim3 b256(256);
        k_fc1_glu_fb<<<EXPERTS * (TOK / BM) * (INTER / 64), b256, 0, stream>>>(X, W1, inter);
        k_fc2_fb    <<<EXPERTS * (TOK / BM) * (HID / 128),  b256, 0, stream>>>(inter, W2, out);
    }
}